// Round 15
// baseline (414.201 us; speedup 1.0000x reference)
//
#include <hip/hip_runtime.h>
#include <hip/hip_bf16.h>
#include <stdint.h>

typedef __bf16 bf16x8 __attribute__((ext_vector_type(8)));
typedef float  f32x4  __attribute__((ext_vector_type(4)));

#define NSLOPE 0.01f

// problem dims
#define NB   32
#define CIN  128
#define HIN  130
#define WIN  130
#define KOUT 256
#define POUT 128
#define QOUT 128
#define HWIN (HIN*WIN)            // 16900
#define PQ   (POUT*QOUT)

// workspace: X' (NHWC bf16) then W'' ([cc,kq,r,s][k 256][ci 32] bf16)
#define XP_BYTES 138444800ull     // 32*130*130*128*2
#define WP_ELEMS (36*256*32)      // 294912

// LDS: W dbuf 2 x 8192 @0 ; X dbuf 2 x 8320 @16384 -> 33024 B, 4 blocks/CU
// 64-B logical rows (32 ci), two rows packed per 128-B line, XOR swizzle bits 4-5.
#define XS_BASE   16384
#define LDS_TOTAL 33024

#define SB0()  __builtin_amdgcn_sched_barrier(0)
#define VMW(n) asm volatile("s_waitcnt vmcnt(" #n ")" ::: "memory")

__device__ __forceinline__ unsigned short f2bf(float f) {
    unsigned u = __builtin_bit_cast(unsigned, f);
    u += 0x7FFFu + ((u >> 16) & 1u);   // RNE
    return (unsigned short)(u >> 16);
}

__device__ __forceinline__ void g2lds16(const void* g, void* l) {
    __builtin_amdgcn_global_load_lds(
        (const __attribute__((address_space(1))) void*)g,
        (__attribute__((address_space(3))) void*)l,
        16, 0, 0);
}

// ---------------- pre-pass: X NCHW fp32 -> NHWC bf16 (blocks < 4160)
//                  + W OIHW fp32 -> W'' (blocks >= 4160) ----------------
__global__ __launch_bounds__(256) void k_conv_xw(const float* __restrict__ X,
                                                 const float* __restrict__ W,
                                                 unsigned short* __restrict__ Xp,
                                                 unsigned short* __restrict__ Wp) {
    __shared__ unsigned int tile[64*131];      // 33536 B
    const int tid = threadIdx.x;

    if (blockIdx.x >= NB*HIN) {                // W-convert tail: 1152 blocks
        int e = (blockIdx.x - NB*HIN)*256 + tid;
        if (e < WP_ELEMS) {
            int ci5 = e & 31;
            int k   = (e >> 5) & 255;
            int srs = e >> 13;                 // 0..35 = ((cc*2+kq)*3+r)*3+s
            int cc = srs / 18;
            int kq = (srs / 9) & 1;
            int rr = (srs / 3) % 3;
            int s  = srs % 3;
            int c  = cc*64 + kq*32 + ci5;
            Wp[e] = f2bf(W[(size_t)k*1152 + (size_t)c*9 + rr*3 + s]);
        }
        return;
    }

    const int b = blockIdx.x;                  // n*130 + h
    const int n = b / 130, h = b - n*130;
    const size_t in0 = (size_t)n*(CIN*(size_t)HWIN) + (size_t)h*WIN;
    for (int fi = tid; fi < 64*130; fi += 256) {
        const int c2 = fi / 130, w = fi - c2*130;
        const float lo = X[in0 + (size_t)(2*c2  )*HWIN + w];
        const float hi = X[in0 + (size_t)(2*c2+1)*HWIN + w];
        tile[c2*131 + w] = (unsigned)f2bf(lo) | ((unsigned)f2bf(hi) << 16);
    }
    __syncthreads();
    unsigned int* outp = (unsigned int*)(Xp + (size_t)b*(WIN*CIN));
    for (int oi = tid; oi < 2080; oi += 256) {           // 130 w x 16 chunks
        const int w = oi >> 4, j4 = (oi & 15) << 2;      // c2 = j4..j4+3
        uint4 v;
        v.x = tile[(j4+0)*131 + w];
        v.y = tile[(j4+1)*131 + w];
        v.z = tile[(j4+2)*131 + w];
        v.w = tile[(j4+3)*131 + w];
        *(uint4*)(outp + w*64 + j4) = v;                 // dword idx = w*64 + c2
    }
}

// ---------------- staging (linear LDS dest, inverse-swizzled global src) ----------------
// granule g: prow=g>>3, off=(g&7)*16; logical row = prow*2 + (off>>6);
// ci-byte c = (off&63) ^ ((prow&3)<<4)
__device__ __forceinline__ void stage_w32(const unsigned short* __restrict__ Wp,
                                          unsigned char* lds, int srs, int kh, int tid) {
    const unsigned short* wb = Wp + (size_t)srs*8192 + (size_t)(kh*128)*32;
    #pragma unroll
    for (int it = 0; it < 4; ++it) {                      // 512 granules
        const int g    = it*128 + tid;
        const int prow = g >> 3;
        const int off  = (g & 7) << 4;
        const int kl   = prow*2 + (off >> 6);             // kout-local 0..127
        const int c    = (off & 63) ^ ((prow & 3) << 4);
        g2lds16(wb + (size_t)kl*32 + (c >> 1), lds + (g << 4));
    }
}

__device__ __forceinline__ void stage_x32(const unsigned short* __restrict__ Xp,
                                          unsigned char* lds, int n, int h,
                                          int cc, int kq, int tid) {
    const unsigned short* xb = Xp + ((size_t)(n*HIN + h)*WIN)*CIN + cc*64 + kq*32;
    #pragma unroll
    for (int it = 0; it < 5; ++it) {                      // 520 granules
        const int g = it*128 + tid;
        if (g < 520) {
            const int prow = g >> 3;
            const int off  = (g & 7) << 4;
            const int w    = prow*2 + (off >> 6);         // 0..129
            const int c    = (off & 63) ^ ((prow & 3) << 4);
            g2lds16(xb + (size_t)w*CIN + (c >> 1), lds + (g << 4));
        }
    }
}

// ---------------- main conv: 128 kout x 128 q, 2 waves of 64x128, 4 blocks/CU ----------------
// K-chunk 32, 36 steps, both tiles double-buffered, counted vmcnt (never 0 mid-loop)
template<int PRIO>
__device__ __forceinline__ void conv_body(
    const unsigned short* __restrict__ Xp,
    const unsigned short* __restrict__ Wp,
    const float* __restrict__ bias,
    float* __restrict__ out,
    unsigned char* smem, int tid, int L)
{
    const int lane = tid & 63;
    const int wm   = tid >> 6;        // 0..1: kout 64-block within the kh-half
    const int l15  = lane & 15;
    const int kg   = lane >> 4;

    const int kh = L & 1;
    const int np = L >> 1;
    const int p  = np & 127;
    const int n  = np >> 7;

    // A-frag base: klocal = wm*64 + mf*16 + l15 -> mf advances +1024 B (swizzle-invariant)
    const int klh   = wm*64 + l15;
    const int aBase = (klh >> 1)*128 + ((klh & 1) << 6)
                    + ((kg*16) ^ (((klh >> 1) & 3) << 4));

    f32x4 acc[4][8];
    #pragma unroll
    for (int i = 0; i < 4; ++i)
        #pragma unroll
        for (int j = 0; j < 8; ++j)
            acc[i][j] = (f32x4){0.f, 0.f, 0.f, 0.f};

    // prologue: X tile 0 (cc0,kq0,r0) + W(0), full drain once
    stage_x32(Xp, smem + XS_BASE, n, p, 0, 0, tid);
    stage_w32(Wp, smem, 0, kh, tid);
    VMW(0);
    __builtin_amdgcn_s_barrier();
    SB0();

    int u = 0;
    #pragma unroll 1
    for (int cw = 0; cw < 4; ++cw) {
        #pragma unroll 1
        for (int r = 0; r < 3; ++r) {
            const int xi = cw*3 + r;
            unsigned char* xs = smem + XS_BASE + (xi & 1)*8320;
            #pragma unroll 1
            for (int s = 0; s < 3; ++s, ++u) {
                unsigned char* wsR = smem + (u & 1)*8192;

                // stage W(u+1) into idle W buffer; counted wait keeps it in flight
                if (u < 35) {
                    stage_w32(Wp, smem + ((u + 1) & 1)*8192, u + 1, kh, tid);
                    VMW(4);   // retire W(u) + any older X; keep W(u+1)'s 4
                } else {
                    VMW(0);
                }
                // X prefetch 2 steps ahead (after VMW so it's never force-drained)
                if (s == 1 && xi < 11) {
                    const int ncw = (r == 2) ? cw + 1 : cw;
                    const int nr  = (r == 2) ? 0 : r + 1;
                    stage_x32(Xp, smem + XS_BASE + ((xi + 1) & 1)*8320,
                              n, p + nr, ncw >> 1, ncw & 1, tid);
                }
                __builtin_amdgcn_s_barrier();
                SB0();

                // B-frag base for this s: w = nf*16 + l15 + s -> nf advances +1024 B
                const int wl    = l15 + s;
                const int bBase = (wl >> 1)*128 + ((wl & 1) << 6)
                                + ((kg*16) ^ (((wl >> 1) & 3) << 4));

                bf16x8 A[4], B[8];
                #pragma unroll
                for (int mf = 0; mf < 4; ++mf)
                    A[mf] = *(const bf16x8*)(wsR + aBase + mf*1024);
                #pragma unroll
                for (int nf = 0; nf < 8; ++nf)
                    B[nf] = *(const bf16x8*)(xs + bBase + nf*1024);

                __builtin_amdgcn_s_setprio(PRIO + 1);
                #pragma unroll
                for (int mf = 0; mf < 4; ++mf)
                    #pragma unroll
                    for (int nf = 0; nf < 8; ++nf)
                        acc[mf][nf] = __builtin_amdgcn_mfma_f32_16x16x32_bf16(
                            A[mf], B[nf], acc[mf][nf], 0, 0, 0);
                __builtin_amdgcn_s_setprio(PRIO);

                SB0();
                __builtin_amdgcn_s_barrier();   // reads done; next step may overwrite
            }
        }
    }

    // epilogue: D col(q) = lane&15, row(kout) = kg*4 + j -> coalesced 64-B segments
    #pragma unroll
    for (int mf = 0; mf < 4; ++mf) {
        const int kb = kh*128 + wm*64 + mf*16 + kg*4;
        const float4 bv = *(const float4*)(bias + kb);
        const float bj[4] = {bv.x, bv.y, bv.z, bv.w};
        #pragma unroll
        for (int nf = 0; nf < 8; ++nf) {
            const int q = nf*16 + l15;
            const size_t base = (((size_t)n*KOUT + kb)*POUT + p)*QOUT + q;
            #pragma unroll
            for (int j = 0; j < 4; ++j) {
                float y = (acc[mf][nf][j] + bj[j]) * 0.5f;
                out[base + (size_t)j*PQ] = (y >= 0.f) ? y : y*NSLOPE;
            }
        }
    }
}

__global__ __launch_bounds__(128, 2) void k_conv_main(
    const unsigned short* __restrict__ Xp,
    const unsigned short* __restrict__ Wp,
    const float* __restrict__ bias,
    float* __restrict__ out)
{
    __shared__ __align__(16) unsigned char smem[LDS_TOTAL];

    // grid 8192 = 8 XCD-chunks x 1024; L = n*256 + p*2 + kh (kh pairs adjacent, same XCD)
    const int L = ((blockIdx.x & 7) << 10) | (blockIdx.x >> 3);

    if (blockIdx.x & 1) {
        __builtin_amdgcn_s_setprio(1);
        conv_body<1>(Xp, Wp, bias, out, smem, threadIdx.x, L);
    } else {
        conv_body<0>(Xp, Wp, bias, out, smem, threadIdx.x, L);
    }
}

extern "C" void kernel_launch(void* const* d_in, const int* in_sizes, int n_in,
                              void* d_out, int out_size, void* d_ws, size_t ws_size,
                              hipStream_t stream) {
    const float* X = (const float*)d_in[0];
    const float* W = (const float*)d_in[1];
    const float* B = (const float*)d_in[2];
    float* out = (float*)d_out;
    unsigned short* Xp = (unsigned short*)d_ws;
    unsigned short* Wp = (unsigned short*)((char*)d_ws + XP_BYTES);

    k_conv_xw  <<<NB*HIN + (WP_ELEMS + 255)/256, 256, 0, stream>>>(X, W, Xp, Wp);
    k_conv_main<<<8192, 128, 0, stream>>>(Xp, Wp, B, out);
}

// Round 16
// 390.597 us; speedup vs baseline: 1.0604x; 1.0604x over previous
//
#include <hip/hip_runtime.h>
#include <hip/hip_bf16.h>
#include <stdint.h>

typedef __bf16 bf16x8 __attribute__((ext_vector_type(8)));
typedef float  f32x4  __attribute__((ext_vector_type(4)));

#define NSLOPE 0.01f

// problem dims
#define NB   32
#define CIN  128
#define HIN  130
#define WIN  130
#define KOUT 256
#define POUT 128
#define QOUT 128
#define HWIN (HIN*WIN)            // 16900
#define PQ   (POUT*QOUT)

// workspace: X' (NHWC bf16) then W' ([rsidx][k 256][ci 64] bf16)
#define XP_BYTES 138444800ull     // 32*130*130*128*2
#define WP_ELEMS (2*3*3*KOUT*64)  // 294912

// LDS (conv): W tile [128 kout][64 ci] = 16384 B @0 ; X tile [130 w][64 ci] = 16640 B @16384
// 33024 B total -> 4 blocks/CU (register ceiling: 2 waves/SIMD at 128 VGPR + 128 acc)
#define XT_OFF    16384
#define LDS_TOTAL (16384 + 16640)

__device__ __forceinline__ unsigned short f2bf(float f) {
    unsigned u = __builtin_bit_cast(unsigned, f);
    u += 0x7FFFu + ((u >> 16) & 1u);   // RNE
    return (unsigned short)(u >> 16);
}

__device__ __forceinline__ void g2lds16(const void* g, void* l) {
    __builtin_amdgcn_global_load_lds(
        (const __attribute__((address_space(1))) void*)g,
        (__attribute__((address_space(3))) void*)l,
        16, 0, 0);
}

// ---------------- pre-pass: X NCHW fp32 -> NHWC bf16 (blocks < 4160)
//                  + W OIHW fp32 -> W' [rsidx][k][ci] (blocks >= 4160) ----------------
__global__ __launch_bounds__(256) void k_conv_xw(const float* __restrict__ X,
                                                 const float* __restrict__ W,
                                                 unsigned short* __restrict__ Xp,
                                                 unsigned short* __restrict__ Wp) {
    __shared__ unsigned int tile[64*131];      // 33536 B
    const int tid = threadIdx.x;

    if (blockIdx.x >= NB*HIN) {                // W-convert tail: 1152 blocks
        int e = (blockIdx.x - NB*HIN)*256 + tid;
        if (e < WP_ELEMS) {
            int ci = e & 63;
            int k  = (e >> 6) & 255;
            int rsIdx = e >> 14;               // 0..17 = cc*9 + r*3 + s
            int cc = rsIdx / 9; int rem = rsIdx - cc*9; int r = rem / 3, s = rem - r*3;
            int c = cc*64 + ci;
            Wp[e] = f2bf(W[(size_t)k*1152 + (size_t)c*9 + r*3 + s]);
        }
        return;
    }

    const int b = blockIdx.x;                  // n*130 + h
    const int n = b / 130, h = b - n*130;
    const size_t in0 = (size_t)n*(CIN*(size_t)HWIN) + (size_t)h*WIN;
    for (int fi = tid; fi < 64*130; fi += 256) {
        const int c2 = fi / 130, w = fi - c2*130;
        const float lo = X[in0 + (size_t)(2*c2  )*HWIN + w];
        const float hi = X[in0 + (size_t)(2*c2+1)*HWIN + w];
        tile[c2*131 + w] = (unsigned)f2bf(lo) | ((unsigned)f2bf(hi) << 16);
    }
    __syncthreads();
    unsigned int* outp = (unsigned int*)(Xp + (size_t)b*(WIN*CIN));
    for (int oi = tid; oi < 2080; oi += 256) {           // 130 w x 16 chunks
        const int w = oi >> 4, j4 = (oi & 15) << 2;      // c2 = j4..j4+3
        uint4 v;
        v.x = tile[(j4+0)*131 + w];
        v.y = tile[(j4+1)*131 + w];
        v.z = tile[(j4+2)*131 + w];
        v.w = tile[(j4+3)*131 + w];
        *(uint4*)(outp + w*64 + j4) = v;                 // dword idx = w*64 + c2
    }
}

// ---------------- main conv body (R10/R12 structure), templated on base priority ----------------
// swizzle: phys = logical ^ ((row&7)<<4), rows are 128 B
template<int PRIO>
__device__ __forceinline__ void conv_body(
    const unsigned short* __restrict__ Xp,
    const unsigned short* __restrict__ Wp,
    const float* __restrict__ bias,
    float* __restrict__ out,
    unsigned char* smem, int tid, int L)
{
    const int lane = tid & 63;
    const int wm   = tid >> 6;        // 0..1: kout 64-block within the kh-half
    const int l15  = lane & 15;
    const int kg16 = (lane >> 4) << 4;

    const int kh = L & 1;
    const int np = L >> 1;
    const int p  = np & 127;
    const int n  = np >> 7;

    f32x4 acc[4][8];
    #pragma unroll
    for (int i = 0; i < 4; ++i)
        #pragma unroll
        for (int j = 0; j < 8; ++j)
            acc[i][j] = (f32x4){0.f, 0.f, 0.f, 0.f};

    #pragma unroll 1
    for (int t = 0; t < 18; ++t) {
        const int cc = t / 9;
        const int rem = t - cc*9;
        const int r  = rem / 3;
        const int s  = rem - r*3;

        __syncthreads();   // all reads of both tiles from previous step complete

        {   // stage W(cc,r,s): 1024 granules over 128 threads
            const unsigned short* wbase = Wp + (size_t)t*(KOUT*64) + (size_t)(kh*128)*64;
            #pragma unroll
            for (int it = 0; it < 8; ++it) {
                const int g    = it*128 + tid;
                const int phys = g << 4;
                const int row  = phys >> 7;                      // kout-local 0..127
                const int cib  = (phys & 127) ^ ((row & 7) << 4);
                g2lds16(wbase + (size_t)row*64 + (cib >> 1), smem + phys);
            }
        }
        if (s == 0) {   // stage X(cc, p+r): 1040 granules
            const unsigned short* xbase =
                Xp + ((size_t)((n*HIN + (p + r))*WIN))*CIN + cc*64;
            #pragma unroll
            for (int it = 0; it < 9; ++it) {
                const int g = it*128 + tid;
                if (g < 1040) {
                    const int phys = g << 4;
                    const int w    = phys >> 7;                  // 0..129
                    const int cib  = (phys & 127) ^ ((w & 7) << 4);
                    g2lds16(xbase + (size_t)w*CIN + (cib >> 1), smem + XT_OFF + phys);
                }
            }
        }

        __syncthreads();   // drains vmcnt: tiles ready

        #pragma unroll
        for (int kq = 0; kq < 2; ++kq) {
            const int cib0 = kq*64 + kg16;
            bf16x8 A[4], B[8];
            #pragma unroll
            for (int mf = 0; mf < 4; ++mf) {
                const int row = wm*64 + mf*16 + l15;
                A[mf] = *(const bf16x8*)(smem + row*128 + (cib0 ^ ((row & 7) << 4)));
            }
            #pragma unroll
            for (int nf = 0; nf < 8; ++nf) {
                const int g = nf*16 + l15 + s;                   // w = q + s
                B[nf] = *(const bf16x8*)(smem + XT_OFF + g*128 + (cib0 ^ ((g & 7) << 4)));
            }
            __builtin_amdgcn_s_setprio(PRIO + 1);
            #pragma unroll
            for (int mf = 0; mf < 4; ++mf)
                #pragma unroll
                for (int nf = 0; nf < 8; ++nf)
                    acc[mf][nf] = __builtin_amdgcn_mfma_f32_16x16x32_bf16(
                        A[mf], B[nf], acc[mf][nf], 0, 0, 0);
            __builtin_amdgcn_s_setprio(PRIO);
        }
    }

    // epilogue: D col(q) = lane&15, row(kout) = kg*4 + j -> coalesced 64-B segments
    const int kg = lane >> 4;
    #pragma unroll
    for (int mf = 0; mf < 4; ++mf) {
        const int kb = kh*128 + wm*64 + mf*16 + kg*4;
        const float4 bv = *(const float4*)(bias + kb);
        const float bj[4] = {bv.x, bv.y, bv.z, bv.w};
        #pragma unroll
        for (int nf = 0; nf < 8; ++nf) {
            const int q = nf*16 + l15;
            const size_t base = (((size_t)n*KOUT + kb)*POUT + p)*QOUT + q;
            #pragma unroll
            for (int j = 0; j < 4; ++j) {
                float y = (acc[mf][nf][j] + bj[j]) * 0.5f;
                out[base + (size_t)j*PQ] = (y >= 0.f) ? y : y*NSLOPE;
            }
        }
    }
}

// 128 kout x 128 q, 2 waves of 64x128, 4 blocks/CU; block-parity base priority
__global__ __launch_bounds__(128, 2) void k_conv_main(
    const unsigned short* __restrict__ Xp,
    const unsigned short* __restrict__ Wp,
    const float* __restrict__ bias,
    float* __restrict__ out)
{
    __shared__ __align__(16) unsigned char smem[LDS_TOTAL];

    // grid 8192 = 8 XCD-chunks x 1024; L = n*256 + p*2 + kh (kh pairs adjacent, same XCD)
    const int L = ((blockIdx.x & 7) << 10) | (blockIdx.x >> 3);

    // parity by ORIGINAL blockIdx: resident blocks on a CU are dispatch-consecutive,
    // so base priority alternates across co-resident blocks -> forced phase asymmetry
    if (blockIdx.x & 1) {
        __builtin_amdgcn_s_setprio(1);
        conv_body<1>(Xp, Wp, bias, out, smem, threadIdx.x, L);
    } else {
        conv_body<0>(Xp, Wp, bias, out, smem, threadIdx.x, L);
    }
}

extern "C" void kernel_launch(void* const* d_in, const int* in_sizes, int n_in,
                              void* d_out, int out_size, void* d_ws, size_t ws_size,
                              hipStream_t stream) {
    const float* X = (const float*)d_in[0];
    const float* W = (const float*)d_in[1];
    const float* B = (const float*)d_in[2];
    float* out = (float*)d_out;
    unsigned short* Xp = (unsigned short*)d_ws;
    unsigned short* Wp = (unsigned short*)((char*)d_ws + XP_BYTES);

    k_conv_xw  <<<NB*HIN + (WP_ELEMS + 255)/256, 256, 0, stream>>>(X, W, Xp, Wp);
    k_conv_main<<<8192, 128, 0, stream>>>(Xp, Wp, B, out);
}